// Round 1
// baseline (44.163 us; speedup 1.0000x reference)
//
#include <hip/hip_runtime.h>

#define HH 512
#define WW 512
#define NIMG 128                    // 16*8 channel-images
#define STRIP 16                    // output rows per wave
#define STRIPS_PER_IMG (HH / STRIP) // 32
#define NTASKS (NIMG * STRIPS_PER_IMG) // 4096 wave tasks
#define BLOCK 256
#define WAVES_PER_BLOCK (BLOCK / 64)
#define NBLOCKS (NTASKS / WAVES_PER_BLOCK) // 1024
#define NTOTAL (16.0 * 8.0 * 512.0 * 512.0)

// Per-wave: one 512-wide row strip, rolling erosion/dilation state.
// re[j] = min(x[j-1],x[j]) (col-eroded row), er = min(re_prev, re_cur),
// d[j] = max(er[j], er[j+1]), op_row[a-1] = max(d_prev, d_cur).
__global__ __launch_bounds__(BLOCK) void opening_partial(
    const float* __restrict__ x, float* __restrict__ partial)
{
    const int tid   = blockIdx.x * BLOCK + threadIdx.x;
    const int wave  = tid >> 6;
    const int lane  = threadIdx.x & 63;
    const int img   = wave / STRIPS_PER_IMG;
    const int strip = wave % STRIPS_PER_IMG;
    const int r0 = strip * STRIP;
    const int r1 = r0 + STRIP;

    const float* base = x + (size_t)img * (HH * WW) + lane * 8;

    float xp[8];   // previous row's x (row a-1)
    float rp[9];   // previous row's re (9 cols: own 8 + right edge col)
    float dp[8];   // previous row's d
    float acc = 0.f;

    // ---- prologue: re_prev from row max(r0-1, 0)  (clamp => er[0]=re[0]) ----
    {
        const int ar = (r0 > 0) ? (r0 - 1) : 0;
        const float4* p = (const float4*)(base + (size_t)ar * WW);
        float4 a0 = p[0], a1 = p[1];
        float xn[8] = {a0.x, a0.y, a0.z, a0.w, a1.x, a1.y, a1.z, a1.w};
        float xm1 = __shfl_up(xn[7], 1);
        if (lane == 0) xm1 = xn[0];              // col clamp (left)
        float xr = __shfl_down(xn[0], 1);
        rp[0] = fminf(xm1, xn[0]);
#pragma unroll
        for (int j = 1; j < 8; ++j) rp[j] = fminf(xn[j - 1], xn[j]);
        rp[8] = (lane == 63) ? rp[7] : fminf(xn[7], xr);
    }

    // ---- main loop: rows r0 .. r1-1 (all guaranteed < H) ----
#pragma unroll 4
    for (int a = r0; a < r1; ++a) {
        const float4* p = (const float4*)(base + (size_t)a * WW);
        float4 a0 = p[0], a1 = p[1];
        float xn[8] = {a0.x, a0.y, a0.z, a0.w, a1.x, a1.y, a1.z, a1.w};
        float xm1 = __shfl_up(xn[7], 1);
        if (lane == 0) xm1 = xn[0];
        float xr = __shfl_down(xn[0], 1);
        float rc[9], er[9], d[8];
        rc[0] = fminf(xm1, xn[0]);
#pragma unroll
        for (int j = 1; j < 8; ++j) rc[j] = fminf(xn[j - 1], xn[j]);
        rc[8] = (lane == 63) ? rc[7] : fminf(xn[7], xr);
#pragma unroll
        for (int j = 0; j < 9; ++j) er[j] = fminf(rp[j], rc[j]);
#pragma unroll
        for (int j = 0; j < 8; ++j) d[j] = fmaxf(er[j], er[j + 1]);
        if (a > r0) {
#pragma unroll
            for (int j = 0; j < 8; ++j) {
                float op = fmaxf(dp[j], d[j]);
                float df = xp[j] - op;
                acc = fmaf(df, df, acc);
            }
        }
#pragma unroll
        for (int j = 0; j < 9; ++j) rp[j] = rc[j];
#pragma unroll
        for (int j = 0; j < 8; ++j) { dp[j] = d[j]; xp[j] = xn[j]; }
    }

    // ---- epilogue: emit op[r1-1] = max(d[r1-1], d[r1]) ----
    if (r1 < HH) {
        // need d row r1: load row r1
        const float4* p = (const float4*)(base + (size_t)r1 * WW);
        float4 a0 = p[0], a1 = p[1];
        float xn[8] = {a0.x, a0.y, a0.z, a0.w, a1.x, a1.y, a1.z, a1.w};
        float xm1 = __shfl_up(xn[7], 1);
        if (lane == 0) xm1 = xn[0];
        float xr = __shfl_down(xn[0], 1);
        float rc[9], er[9];
        rc[0] = fminf(xm1, xn[0]);
#pragma unroll
        for (int j = 1; j < 8; ++j) rc[j] = fminf(xn[j - 1], xn[j]);
        rc[8] = (lane == 63) ? rc[7] : fminf(xn[7], xr);
#pragma unroll
        for (int j = 0; j < 9; ++j) er[j] = fminf(rp[j], rc[j]);
#pragma unroll
        for (int j = 0; j < 8; ++j) {
            float d  = fmaxf(er[j], er[j + 1]);
            float op = fmaxf(dp[j], d);
            float df = xp[j] - op;
            acc = fmaf(df, df, acc);
        }
    } else {
        // bottom of image: row-clamp => d[H] = d[H-1] => op[H-1] = d[H-1]
#pragma unroll
        for (int j = 0; j < 8; ++j) {
            float df = xp[j] - dp[j];
            acc = fmaf(df, df, acc);
        }
    }

    // ---- deterministic wave reduction, one partial per wave ----
#pragma unroll
    for (int off = 32; off; off >>= 1) acc += __shfl_down(acc, off);
    if (lane == 0) partial[wave] = acc;
}

// Single-wave deterministic final reduction in double.
__global__ __launch_bounds__(64) void reduce_final(
    const float* __restrict__ partial, float* __restrict__ out)
{
    const int lane = threadIdx.x;
    double s = 0.0;
    for (int i = lane; i < NTASKS; i += 64) s += (double)partial[i];
#pragma unroll
    for (int off = 32; off; off >>= 1) s += __shfl_down(s, off);
    if (lane == 0) out[0] = (float)(s / NTOTAL);
}

extern "C" void kernel_launch(void* const* d_in, const int* in_sizes, int n_in,
                              void* d_out, int out_size, void* d_ws, size_t ws_size,
                              hipStream_t stream)
{
    const float* x = (const float*)d_in[0];
    float* partial = (float*)d_ws;   // NTASKS floats = 16 KB
    float* out = (float*)d_out;

    opening_partial<<<NBLOCKS, BLOCK, 0, stream>>>(x, partial);
    reduce_final<<<1, 64, 0, stream>>>(partial, out);
}

// Round 2
// 32.946 us; speedup vs baseline: 1.3405x; 1.3405x over previous
//
#include <hip/hip_runtime.h>

#define HH 512
#define WW 512
#define NIMG 128                      // 16*8 channel-images
#define STRIP 8                       // output rows per wave task
#define SPI (HH / STRIP)              // 64 strips per image
#define NTASK (NIMG * SPI)            // 8192 wave tasks
#define BLOCK 256
#define WPB (BLOCK / 64)              // 4 waves per block
#define NBLK (NTASK / WPB)            // 2048 blocks
#define NTOTAL (16.0 * 8.0 * 512.0 * 512.0)

// Grey opening (2x2 flat SE, scipy origin conv) fused with MSE partial sums.
// Lane owns cols [4i,4i+4) (group A) and [256+4i,256+4i+4) (group B):
// both per-row float4 loads are each a fully-contiguous 1KB wave access.
// re[c]=min(x[c-1],x[c]); er=min(re_prev_row,re_cur_row); d[c]=max(er[c],er[c+1]);
// op[row a-1]=max(d_prev,d_cur); acc += (x - op)^2.
__global__ __launch_bounds__(BLOCK) void opening_partial(
    const float* __restrict__ x, float* __restrict__ partial)
{
    const int lane  = threadIdx.x & 63;
    const int wid   = (blockIdx.x * BLOCK + threadIdx.x) >> 6;
    const int img   = wid >> 6;        // / SPI
    const int strip = wid & (SPI - 1); // % SPI
    const int r0  = strip * STRIP;
    const bool top = (strip == 0);
    const bool bot = (strip == SPI - 1);

    const float* ib = x + (size_t)img * (HH * WW);
    const int cA = lane * 4;
    const int cB = 256 + lane * 4;

    float bA[3][4], bB[3][4];          // triple-buffered row registers

#define LOADROW(s, r)                                                   \
    do {                                                                \
        const float4 _a = *(const float4*)(ib + (size_t)(r) * WW + cA); \
        const float4 _b = *(const float4*)(ib + (size_t)(r) * WW + cB); \
        bA[s][0] = _a.x; bA[s][1] = _a.y; bA[s][2] = _a.z; bA[s][3] = _a.w; \
        bB[s][0] = _b.x; bB[s][1] = _b.y; bB[s][2] = _b.z; bB[s][3] = _b.w; \
    } while (0)

    // column-eroded row (re) from buffer slot s -> rcA[5], rcB[5]
#define RCROW(s, rcA, rcB)                                              \
    do {                                                                \
        const float a0 = bA[s][0], a1 = bA[s][1], a2 = bA[s][2], a3 = bA[s][3]; \
        const float b0 = bB[s][0], b1 = bB[s][1], b2 = bB[s][2], b3 = bB[s][3]; \
        float upA = __shfl_up(a3, 1);   if (lane == 0)  upA = a0;       \
        float dnA = __shfl_down(a0, 1);                                 \
        const float bcB0 = __shfl(b0, 0);                               \
        if (lane == 63) dnA = bcB0;                                     \
        float upB = __shfl_up(b3, 1);                                   \
        const float bcA3 = __shfl(a3, 63);                              \
        if (lane == 0)  upB = bcA3;                                     \
        const float dnB = __shfl_down(b0, 1);                           \
        rcA[0] = fminf(upA, a0); rcA[1] = fminf(a0, a1);                \
        rcA[2] = fminf(a1, a2);  rcA[3] = fminf(a2, a3);                \
        rcA[4] = fminf(a3, dnA);                                        \
        rcB[0] = fminf(upB, b0); rcB[1] = fminf(b0, b1);                \
        rcB[2] = fminf(b1, b2);  rcB[3] = fminf(b2, b3);                \
        rcB[4] = (lane == 63) ? rcB[3] : fminf(b3, dnB);                \
    } while (0)

    float rpA[5], rpB[5];   // re of previous row
    float dpA[4], dpB[4];   // d  of previous row
    float xpA[4], xpB[4];   // x  of previous row
    float acc = 0.f;

    // prologue: issue 3 rows immediately (pr, r0, r0+1)
    const int pr = top ? 0 : (r0 - 1);
    LOADROW(0, pr);
    LOADROW(1, r0);
    LOADROW(2, r0 + 1);
    RCROW(0, rpA, rpB);

#pragma unroll
    for (int k = 0; k < STRIP; ++k) {
        const int cur = (k + 1) % 3;   // slot holding row r0+k (static)
        float rcA[5], rcB[5];
        RCROW(cur, rcA, rcB);
        float xA[4], xB[4];
#pragma unroll
        for (int j = 0; j < 4; ++j) { xA[j] = bA[cur][j]; xB[j] = bB[cur][j]; }
        if (k < STRIP - 1) {           // prefetch row r0+k+2, depth-2 ahead
            const int rr = r0 + k + 2;
            LOADROW(k % 3, (rr < HH) ? rr : (HH - 1));
        }
        float erA[5], erB[5], dA[4], dB[4];
#pragma unroll
        for (int j = 0; j < 5; ++j) { erA[j] = fminf(rpA[j], rcA[j]); erB[j] = fminf(rpB[j], rcB[j]); }
#pragma unroll
        for (int j = 0; j < 4; ++j) { dA[j] = fmaxf(erA[j], erA[j + 1]); dB[j] = fmaxf(erB[j], erB[j + 1]); }
        if (k > 0) {                   // emit op[row a-1], accumulate MSE
#pragma unroll
            for (int j = 0; j < 4; ++j) {
                const float oA = fmaxf(dpA[j], dA[j]);
                const float oB = fmaxf(dpB[j], dB[j]);
                const float fA = xpA[j] - oA;
                const float fB = xpB[j] - oB;
                acc = fmaf(fA, fA, acc);
                acc = fmaf(fB, fB, acc);
            }
        }
#pragma unroll
        for (int j = 0; j < 5; ++j) { rpA[j] = rcA[j]; rpB[j] = rcB[j]; }
#pragma unroll
        for (int j = 0; j < 4; ++j) {
            dpA[j] = dA[j]; dpB[j] = dB[j];
            xpA[j] = xA[j]; xpB[j] = xB[j];
        }
    }

    // epilogue: emit row r1-1
    if (!bot) {
        // row r1 sits in slot (STRIP-2)%3 == 0 (loaded by body k=6)
        float rcA[5], rcB[5];
        RCROW(0, rcA, rcB);
        float erA[5], erB[5];
#pragma unroll
        for (int j = 0; j < 5; ++j) { erA[j] = fminf(rpA[j], rcA[j]); erB[j] = fminf(rpB[j], rcB[j]); }
#pragma unroll
        for (int j = 0; j < 4; ++j) {
            const float dA = fmaxf(erA[j], erA[j + 1]);
            const float dB = fmaxf(erB[j], erB[j + 1]);
            const float fA = xpA[j] - fmaxf(dpA[j], dA);
            const float fB = xpB[j] - fmaxf(dpB[j], dB);
            acc = fmaf(fA, fA, acc);
            acc = fmaf(fB, fB, acc);
        }
    } else {
        // bottom row clamp: op[H-1] = d[H-1]
#pragma unroll
        for (int j = 0; j < 4; ++j) {
            const float fA = xpA[j] - dpA[j];
            const float fB = xpB[j] - dpB[j];
            acc = fmaf(fA, fA, acc);
            acc = fmaf(fB, fB, acc);
        }
    }

    // deterministic: wave shfl reduce -> LDS -> fixed-order block sum
    __shared__ float wsum[WPB];
#pragma unroll
    for (int off = 32; off; off >>= 1) acc += __shfl_down(acc, off);
    if (lane == 0) wsum[threadIdx.x >> 6] = acc;
    __syncthreads();
    if (threadIdx.x == 0)
        partial[blockIdx.x] = (wsum[0] + wsum[1]) + (wsum[2] + wsum[3]);
#undef LOADROW
#undef RCROW
}

// Deterministic final reduction: 2048 partials, one 256-thread block, f64 tree.
__global__ __launch_bounds__(256) void reduce_final(
    const float* __restrict__ partial, float* __restrict__ out)
{
    __shared__ double sm[256];
    const int t = threadIdx.x;
    double s = 0.0;
#pragma unroll
    for (int i = 0; i < NBLK / 256; ++i) s += (double)partial[t + 256 * i];
    sm[t] = s;
    __syncthreads();
    for (int h = 128; h > 0; h >>= 1) {
        if (t < h) sm[t] += sm[t + h];
        __syncthreads();
    }
    if (t == 0) out[0] = (float)(sm[0] / NTOTAL);
}

extern "C" void kernel_launch(void* const* d_in, const int* in_sizes, int n_in,
                              void* d_out, int out_size, void* d_ws, size_t ws_size,
                              hipStream_t stream)
{
    const float* x = (const float*)d_in[0];
    float* partial = (float*)d_ws;     // NBLK floats = 8 KB scratch
    float* out = (float*)d_out;

    opening_partial<<<NBLK, BLOCK, 0, stream>>>(x, partial);
    reduce_final<<<1, 256, 0, stream>>>(partial, out);
}